// Round 2
// baseline (196.244 us; speedup 1.0000x reference)
//
#include <hip/hip_runtime.h>
#include <math.h>

// CTC forward (keras ctc_batch_cost), B=1024 T=256 C=128 L=64, S=129.
// One wave64 per batch element, zero barriers.
// R7 = R6 theory (L2 prefetch stream 7 chunks ahead of the LDS ring) with
// the hazard fixed: prefetch is a size-4 global_load_lds into a dead 256B
// LDS scratch (no dest VGPR -> no async clobber; R6's inline-asm
// global_load_dword let the compiler reuse the dest VGPR while the load
// was in flight -> memory fault).
//  - ring: 7 chunks (28 x 16B global_load_lds) in flight, manual vmcnt.
//  - prefetch: 1 load/chunk, 64B/lane stride touches all lines of the 4KB
//    chunk; doubles in-flight HBM demand (~56KB/wave) so ring loads hit L2.
//  - q-values register-prefetched one chunk ahead; per-step chain is pure
//    VALU + one DPP shift.
//  - Probability-domain semiring with x128 bias, renorm every 8 steps.
// vmcnt ledger ([1 prefetch + 4 ring] = 5 events/slot): prologue 35 out,
// chunk0 at <=30, steady wait 25, tail 25,25,24,23,22,21,20,20,20,16,12,8,4,0.

#define Bn 1024
#define Tn 256
#define Cn 128
#define Ln 64
#define BLANK 127
#define U 8
#define NC (Tn / U)       // 32 chunks
#define RING 8
#define DEPTH 7           // ring chunks in flight
#define EPS128 (1e-7f * 128.0f)
#define LN2 0.69314718055994530942f

// s_waitcnt imm: vmcnt bits [3:0]+[15:14]; expcnt[6:4]=7, lgkmcnt[11:8]=0xF don't-care
#define WAIT_VM(n) __builtin_amdgcn_s_waitcnt((((n) & 0xF) | (((n) >> 4) << 14)) | 0x0F70)
#define SCHED_FENCE() __builtin_amdgcn_sched_barrier(0)

template <int CTRL>
__device__ __forceinline__ float dpp_movf(float x) {
    return __int_as_float(__builtin_amdgcn_update_dpp(
        0, __float_as_int(x), CTRL, 0xF, 0xF, true));
}
__device__ __forceinline__ int dpp_shr1_i(int x) {
    return __builtin_amdgcn_update_dpp(0, x, 0x138, 0xF, 0xF, true);
}
__device__ __forceinline__ void dma16(const float* g, float* l) {
    __builtin_amdgcn_global_load_lds(
        (const __attribute__((address_space(1))) void*)g,
        (__attribute__((address_space(3))) void*)l, 16, 0, 0);
}
__device__ __forceinline__ void dma4(const float* g, float* l) {
    __builtin_amdgcn_global_load_lds(
        (const __attribute__((address_space(1))) void*)g,
        (__attribute__((address_space(3))) void*)l, 4, 0, 0);
}

__global__ __launch_bounds__(64)
void ctc_ring_kernel(const int* __restrict__ y_true,
                     const float* __restrict__ y_pred,
                     float* __restrict__ out) {
    __shared__ __align__(16) float ring[RING][U * Cn];   // 32 KB
    __shared__ __align__(16) float scratch[64];          // dead prefetch sink
    const int b = blockIdx.x;
    const int i = threadIdx.x;

    const int li = y_true[b * Ln + i];
    const int ll = dpp_shr1_i(li);                 // lab[i-1] (lane0 -> 0)
    const float skf = (li != ll) ? 1.0f : 0.0f;

    const float* gb = y_pred + (size_t)b * (Tn * Cn);

    auto issue_chunk = [&](int c) {
        const float* g = gb + c * (U * Cn);
        float* l = ring[c & (RING - 1)];
#pragma unroll
        for (int k = 0; k < 4; ++k)                // 4 x (64 lanes x 16B) = 4 KB
            dma16(g + k * 256 + i * 4, l + k * 256);
    };

    // L2 prefetch: per-lane global addr at 64B stride covers the whole 4KB
    // chunk; dest is the dead LDS scratch (wave-uniform base + lane*4).
    // Exactly 1 vmcnt event, no dest VGPR.
    auto prefetch_chunk = [&](int c) {
        dma4(gb + c * (U * Cn) + i * 16, scratch);
    };

    float qlA[U], qbA[U], qlB[U], qbB[U];
    auto qread = [&](int c, float* ql, float* qb) {
        const float* s = ring[c & (RING - 1)];
#pragma unroll
        for (int j = 0; j < U; ++j) {
            ql[j] = fmaf(s[j * Cn + li],    128.0f, EPS128);
            qb[j] = fmaf(s[j * Cn + BLANK], 128.0f, EPS128);
        }
    };

    float E = 0.f, O = 0.f, X = 0.f;   // states 2i, 2i+1, 128(lane63)
    int Esum = 0;

    auto steps = [&](const float* ql, const float* qb, bool first) {
#pragma unroll
        for (int j = 0; j < U; ++j) {
            if (first && j == 0) {                 // t=0: only states 0,1
                E = (i == 0) ? qb[0] : 0.f;
                O = (i == 0) ? ql[0] : 0.f;
                X = 0.f;
                continue;
            }
            const float Ol = dpp_movf<0x138>(O);   // state 2i-1 from left
            const float t1 = O + E;
            const float nO = fmaf(skf, Ol, t1) * ql[j];
            const float nE = (E + Ol) * qb[j];
            const float nX = (X + O) * qb[j];
            E = nE; O = nO; X = nX;
        }
    };
    auto renorm = [&]() {
        float m = fmaxf(E, O);
        if (i == 63) m = fmaxf(m, X);
        m = fmaxf(m, dpp_movf<0x111>(m));
        m = fmaxf(m, dpp_movf<0x112>(m));
        m = fmaxf(m, dpp_movf<0x114>(m));
        m = fmaxf(m, dpp_movf<0x118>(m));
        m = fmaxf(m, dpp_movf<0x142>(m));
        m = fmaxf(m, dpp_movf<0x143>(m));          // lane63 = wave max
        const unsigned ub =
            (unsigned)__builtin_amdgcn_readlane(__float_as_int(m), 63);
        const int eb = (int)(ub >> 23);
        const float sc = __int_as_float((unsigned)(254 - eb) << 23);
        Esum += eb - 127;
        E *= sc; O *= sc; X *= sc;
    };

    // ---- prologue: prefetch 7..13 to L2, ring-load 0..6 (35 events out) ----
#pragma unroll
    for (int c = 0; c < DEPTH; ++c) {
        prefetch_chunk(c + DEPTH);                 // chunks 7..13
        issue_chunk(c);                            // chunks 0..6
    }
    WAIT_VM(30); SCHED_FENCE();      // ring chunk 0 landed
    qread(0, qlA, qbA);

    // ---- slot 0 ----
    WAIT_VM(25); SCHED_FENCE();      // ring chunk 1 landed
    qread(1, qlB, qbB);
    prefetch_chunk(14); issue_chunk(7);
    steps(qlA, qbA, true);           // chunk 0
    renorm();

    // ---- slots 1..16 (steady: wait 25, issue P(s+14)+R(s+7)) ----
    for (int cc = 1; cc <= 15; cc += 2) {
        WAIT_VM(25); SCHED_FENCE();  // ring chunk cc+1 landed
        qread(cc + 1, qlA, qbA);
        prefetch_chunk(cc + 14); issue_chunk(cc + 7);
        steps(qlB, qbB, false);      // chunk cc
        renorm();
        WAIT_VM(25); SCHED_FENCE();  // ring chunk cc+2 landed
        qread(cc + 2, qlB, qbB);
        prefetch_chunk(cc + 15); issue_chunk(cc + 8);
        steps(qlA, qbA, false);      // chunk cc+1
        renorm();
    }
    // B holds chunk 17's q-values; ring issued through 23; prefetch through 30.

    // ---- tail slots 17..31: per-slot exact vmcnt ----
    WAIT_VM(25); SCHED_FENCE();      // 18 landed
    qread(18, qlA, qbA); prefetch_chunk(31); issue_chunk(24);
    steps(qlB, qbB, false); renorm();                        // 17
    WAIT_VM(25); SCHED_FENCE();      // 19 landed
    qread(19, qlB, qbB); issue_chunk(25);
    steps(qlA, qbA, false); renorm();                        // 18
    WAIT_VM(24); SCHED_FENCE();      // 20 landed
    qread(20, qlA, qbA); issue_chunk(26);
    steps(qlB, qbB, false); renorm();                        // 19
    WAIT_VM(23); SCHED_FENCE();      // 21 landed
    qread(21, qlB, qbB); issue_chunk(27);
    steps(qlA, qbA, false); renorm();                        // 20
    WAIT_VM(22); SCHED_FENCE();      // 22 landed
    qread(22, qlA, qbA); issue_chunk(28);
    steps(qlB, qbB, false); renorm();                        // 21
    WAIT_VM(21); SCHED_FENCE();      // 23 landed
    qread(23, qlB, qbB); issue_chunk(29);
    steps(qlA, qbA, false); renorm();                        // 22
    WAIT_VM(20); SCHED_FENCE();      // 24 landed
    qread(24, qlA, qbA); issue_chunk(30);
    steps(qlB, qbB, false); renorm();                        // 23
    WAIT_VM(20); SCHED_FENCE();      // 25 landed
    qread(25, qlB, qbB); issue_chunk(31);
    steps(qlA, qbA, false); renorm();                        // 24
    WAIT_VM(20); SCHED_FENCE();      // 26 landed
    qread(26, qlA, qbA);
    steps(qlB, qbB, false); renorm();                        // 25
    WAIT_VM(16); SCHED_FENCE();      // 27 landed
    qread(27, qlB, qbB);
    steps(qlA, qbA, false); renorm();                        // 26
    WAIT_VM(12); SCHED_FENCE();      // 28 landed
    qread(28, qlA, qbA);
    steps(qlB, qbB, false); renorm();                        // 27
    WAIT_VM(8); SCHED_FENCE();       // 29 landed
    qread(29, qlB, qbB);
    steps(qlA, qbA, false); renorm();                        // 28
    WAIT_VM(4); SCHED_FENCE();       // 30 landed
    qread(30, qlA, qbA);
    steps(qlB, qbB, false); renorm();                        // 29
    WAIT_VM(0); SCHED_FENCE();       // 31 landed (drain)
    qread(31, qlB, qbB);
    steps(qlA, qbA, false); renorm();                        // 30
    steps(qlB, qbB, false);                                  // 31

    if (i == 63) {
        const float s = O + X;       // alpha[127] + alpha[128] (scaled)
#if __has_builtin(__builtin_amdgcn_logf)
        const float l2 = __builtin_amdgcn_logf(s);
#else
        const float l2 = log2f(s);
#endif
        out[b] = -(l2 + (float)(Esum - 7 * Tn)) * LN2;
    }
}

extern "C" void kernel_launch(void* const* d_in, const int* in_sizes, int n_in,
                              void* d_out, int out_size, void* d_ws, size_t ws_size,
                              hipStream_t stream) {
    const int*   y_true = (const int*)d_in[0];
    const float* y_pred = (const float*)d_in[1];
    float*       out    = (float*)d_out;
    hipLaunchKernelGGL(ctc_ring_kernel, dim3(Bn), dim3(64), 0, stream,
                       y_true, y_pred, out);
}

// Round 3
// 192.674 us; speedup vs baseline: 1.0185x; 1.0185x over previous
//
#include <hip/hip_runtime.h>
#include <math.h>

// CTC forward (keras ctc_batch_cost), B=1024 T=256 C=128 L=64, S=129.
// R8: R5 pipeline (7-deep LDS ring, manual vmcnt, zero barriers) with TWO
// batch elements per block (128 threads = 2 independent wave64s, each with
// its own 32 KB ring half). 512 blocks / 256 CU = 2 blocks/CU x 64 KB LDS
// -> 8 waves/CU = 2 waves/SIMD (was 1). The serial VALU recurrence chain
// (~16 cy/step dependent DPP+FMA) and qread ds_read latency of one wave now
// hide behind the sibling wave's issue stream; per-CU in-flight HBM demand
// doubles to ~224 KB. R7's L2-prefetch stream is dropped (in-order vmcnt
// retirement made prefetch events gate the ring waits; -2% measured).
//  - q-values (label gather + blank) register-prefetched one chunk ahead.
//  - Probability-domain semiring recurrence, x128 bias, wave-uniform renorm
//    every 8 steps (exponent stripped into Esum) -- verified absmax 0.

#define Bn 1024
#define Tn 256
#define Cn 128
#define Ln 64
#define BLANK 127
#define U 8
#define NC (Tn / U)       // 32 chunks
#define RING 8
#define DEPTH 7           // chunks in flight: 7*4 = 28 loads <= 63
#define EPS128 (1e-7f * 128.0f)
#define LN2 0.69314718055994530942f

// s_waitcnt imm: vmcnt bits [3:0]+[15:14]; expcnt[6:4]=7, lgkmcnt[11:8]=0xF don't-care
#define WAIT_VM(n) __builtin_amdgcn_s_waitcnt((((n) & 0xF) | (((n) >> 4) << 14)) | 0x0F70)
#define SCHED_FENCE() __builtin_amdgcn_sched_barrier(0)

template <int CTRL>
__device__ __forceinline__ float dpp_movf(float x) {
    return __int_as_float(__builtin_amdgcn_update_dpp(
        0, __float_as_int(x), CTRL, 0xF, 0xF, true));
}
__device__ __forceinline__ int dpp_shr1_i(int x) {
    return __builtin_amdgcn_update_dpp(0, x, 0x138, 0xF, 0xF, true);
}
__device__ __forceinline__ void dma16(const float* g, float* l) {
    __builtin_amdgcn_global_load_lds(
        (const __attribute__((address_space(1))) void*)g,
        (__attribute__((address_space(3))) void*)l, 16, 0, 0);
}

__global__ __launch_bounds__(128)
void ctc_ring_kernel(const int* __restrict__ y_true,
                     const float* __restrict__ y_pred,
                     float* __restrict__ out) {
    __shared__ __align__(16) float ring[2][RING][U * Cn];   // 64 KB
    const int w = threadIdx.x >> 6;                // wave id within block
    const int i = threadIdx.x & 63;                // lane within wave
    const int b = blockIdx.x * 2 + w;              // batch element

    float (*myring)[U * Cn] = ring[w];

    const int li = y_true[b * Ln + i];
    const int ll = dpp_shr1_i(li);                 // lab[i-1] (lane0 -> 0)
    const float skf = (li != ll) ? 1.0f : 0.0f;

    const float* gb = y_pred + (size_t)b * (Tn * Cn);

    auto issue_chunk = [&](int c) {
        const float* g = gb + c * (U * Cn);
        float* l = myring[c & (RING - 1)];
#pragma unroll
        for (int k = 0; k < 4; ++k)                // 4 x (64 lanes x 16B) = 4 KB
            dma16(g + k * 256 + i * 4, l + k * 256);
    };

    float qlA[U], qbA[U], qlB[U], qbB[U];
    auto qread = [&](int c, float* ql, float* qb) {
        const float* s = myring[c & (RING - 1)];
#pragma unroll
        for (int j = 0; j < U; ++j) {
            ql[j] = fmaf(s[j * Cn + li],    128.0f, EPS128);
            qb[j] = fmaf(s[j * Cn + BLANK], 128.0f, EPS128);
        }
    };

    float E = 0.f, O = 0.f, X = 0.f;   // states 2i, 2i+1, 128(lane63)
    int Esum = 0;

    auto steps = [&](const float* ql, const float* qb, bool first) {
#pragma unroll
        for (int j = 0; j < U; ++j) {
            if (first && j == 0) {                 // t=0: only states 0,1
                E = (i == 0) ? qb[0] : 0.f;
                O = (i == 0) ? ql[0] : 0.f;
                X = 0.f;
                continue;
            }
            const float Ol = dpp_movf<0x138>(O);   // state 2i-1 from left
            const float t1 = O + E;
            const float nO = fmaf(skf, Ol, t1) * ql[j];
            const float nE = (E + Ol) * qb[j];
            const float nX = (X + O) * qb[j];
            E = nE; O = nO; X = nX;
        }
    };
    auto renorm = [&]() {
        float m = fmaxf(E, O);
        if (i == 63) m = fmaxf(m, X);
        m = fmaxf(m, dpp_movf<0x111>(m));
        m = fmaxf(m, dpp_movf<0x112>(m));
        m = fmaxf(m, dpp_movf<0x114>(m));
        m = fmaxf(m, dpp_movf<0x118>(m));
        m = fmaxf(m, dpp_movf<0x142>(m));
        m = fmaxf(m, dpp_movf<0x143>(m));          // lane63 = wave max
        const unsigned ub =
            (unsigned)__builtin_amdgcn_readlane(__float_as_int(m), 63);
        const int eb = (int)(ub >> 23);
        const float sc = __int_as_float((unsigned)(254 - eb) << 23);
        Esum += eb - 127;
        E *= sc; O *= sc; X *= sc;
    };

    // ---- prologue: fill the pipe (chunks 0..6 in flight) ----
#pragma unroll
    for (int c = 0; c < DEPTH; ++c) issue_chunk(c);
    WAIT_VM(24);                     // chunk 0 landed (24 loads still out)
    SCHED_FENCE();
    qread(0, qlA, qbA);

    // ---- steady state: chunks 0..23, issue stays 7 ahead ----
    for (int cc = 0; cc < 24; cc += 2) {
        WAIT_VM(20); SCHED_FENCE();  // chunk cc+1 landed
        qread(cc + 1, qlB, qbB);
        issue_chunk(cc + 7);
        steps(qlA, qbA, cc == 0);    // chunk cc
        renorm();
        WAIT_VM(20); SCHED_FENCE();  // chunk cc+2 landed
        qread(cc + 2, qlA, qbA);
        issue_chunk(cc + 8);
        steps(qlB, qbB, false);      // chunk cc+1
        renorm();
    }
    // issued through 30; completed through 24; qA = chunk 24
    WAIT_VM(20); SCHED_FENCE();      // chunk 25 landed
    qread(25, qlB, qbB);
    issue_chunk(31);
    steps(qlA, qbA, false);          // 24
    renorm();
    WAIT_VM(0); SCHED_FENCE();       // drain: chunks 26..31 all in LDS
    qread(26, qlA, qbA);
    steps(qlB, qbB, false);          // 25
    renorm();
    qread(27, qlB, qbB); steps(qlA, qbA, false); renorm();   // 26
    qread(28, qlA, qbA); steps(qlB, qbB, false); renorm();   // 27
    qread(29, qlB, qbB); steps(qlA, qbA, false); renorm();   // 28
    qread(30, qlA, qbA); steps(qlB, qbB, false); renorm();   // 29
    qread(31, qlB, qbB); steps(qlA, qbA, false); renorm();   // 30
    steps(qlB, qbB, false);                                   // 31

    if (i == 63) {
        const float s = O + X;       // alpha[127] + alpha[128] (scaled)
#if __has_builtin(__builtin_amdgcn_logf)
        const float l2 = __builtin_amdgcn_logf(s);
#else
        const float l2 = log2f(s);
#endif
        out[b] = -(l2 + (float)(Esum - 7 * Tn)) * LN2;
    }
}

extern "C" void kernel_launch(void* const* d_in, const int* in_sizes, int n_in,
                              void* d_out, int out_size, void* d_ws, size_t ws_size,
                              hipStream_t stream) {
    const int*   y_true = (const int*)d_in[0];
    const float* y_pred = (const float*)d_in[1];
    float*       out    = (float*)d_out;
    hipLaunchKernelGGL(ctc_ring_kernel, dim3(Bn / 2), dim3(128), 0, stream,
                       y_true, y_pred, out);
}